// Round 7
// baseline (365.269 us; speedup 1.0000x reference)
//
#include <hip/hip_runtime.h>
#include <hip/hip_fp8.h>
#include <math.h>

#define N_ROWS 8192
#define IN_F   512
#define RFF    2048
#define OUT_F  1000
#define OUT_PAD 1024
#define INV_RFF_SCALAR 0.03125f
#define MEAN_FIELD 25.0f

typedef __attribute__((ext_vector_type(8))) short short8;
typedef __attribute__((ext_vector_type(4))) float f32x4;

// ---------- bf16 helpers (RTN-even) ----------
__device__ __forceinline__ unsigned short f32_to_bf16(float f) {
    unsigned u = __float_as_uint(f);
    unsigned r = 0x7FFFu + ((u >> 16) & 1u);
    return (unsigned short)((u + r) >> 16);
}
__device__ __forceinline__ float bf16_to_f32(unsigned short h) {
    return __uint_as_float(((unsigned)h) << 16);
}
__device__ __forceinline__ unsigned char f32_to_fp8(float x) {
    __hip_fp8_e4m3 q(x);           // OCP e4m3fn, HW RNE convert
    return (unsigned char)q.__x;
}

// fragment-chunk global source address for bf16 operand (row-major, ld=ldx)
__device__ __forceinline__ const uint4* gsrc(const unsigned short* X, int ldx,
                                             int r0, int k0, int q) {
    int rt = q >> 6, L = q & 63;
    int r = r0 + rt * 16 + (L & 15);
    int k = k0 + ((L >> 4) << 3);
    return (const uint4*)(X + (size_t)r * ldx + k);
}

// async global->LDS staging of one 128x32 bf16 tile (512 x 16B chunks).
__device__ __forceinline__ void stage_tile(const unsigned short* __restrict__ X, int ldx,
                                           int r0, int k0, unsigned short* lds,
                                           int w, int lane) {
    #pragma unroll
    for (int half = 0; half < 2; ++half) {
        int qb = half * 256 + w * 64;
        const uint4* g = gsrc(X, ldx, r0, k0, qb + lane);
        __builtin_amdgcn_global_load_lds(
            (const __attribute__((address_space(1))) void*)g,
            (__attribute__((address_space(3))) void*)(lds + qb * 8),
            16, 0, 0);
    }
}

// async staging of one 128x64-byte fp8 tile (512 x 16B chunks).
__device__ __forceinline__ void stage_tile8(const unsigned char* __restrict__ X, int ldb,
                                            int r0, int k0b, unsigned char* lds,
                                            int w, int lane) {
    #pragma unroll
    for (int half = 0; half < 2; ++half) {
        int qb = half * 256 + w * 64;
        int q = qb + lane;
        int rt = q >> 6, L = q & 63;
        int row = r0 + rt * 16 + (L & 15);
        int kb = k0b + ((L >> 4) << 4);
        const void* g = X + (size_t)row * ldb + kb;
        __builtin_amdgcn_global_load_lds(
            (const __attribute__((address_space(1))) void*)g,
            (__attribute__((address_space(3))) void*)(lds + qb * 16),
            16, 0, 0);
    }
}

// ---------------- conversion kernels ----------------
__global__ __launch_bounds__(256) void conv_split_kernel(
    const float* __restrict__ X, unsigned short* __restrict__ H,
    unsigned short* __restrict__ L, int n4)
{
    int i = blockIdx.x * 256 + threadIdx.x;
    if (i >= n4) return;
    float4 v = ((const float4*)X)[i];
    ushort4 h, l;
    h.x = f32_to_bf16(v.x); l.x = f32_to_bf16(v.x - bf16_to_f32(h.x));
    h.y = f32_to_bf16(v.y); l.y = f32_to_bf16(v.y - bf16_to_f32(h.y));
    h.z = f32_to_bf16(v.z); l.z = f32_to_bf16(v.z - bf16_to_f32(h.z));
    h.w = f32_to_bf16(v.w); l.w = f32_to_bf16(v.w - bf16_to_f32(h.w));
    ((ushort4*)H)[i] = h;
    ((ushort4*)L)[i] = l;
}

// cov -> fp8 e4m3 in B^T layout, block-triangular weights {16,8,0} (blk=128),
// with exact-diagonal entries (n==k) zeroed — those are added exactly in the
// fused epilogue from Cd[] and bf16 Phi.
__global__ __launch_bounds__(256) void conv_covu8_kernel(
    const float* __restrict__ X, unsigned char* __restrict__ O)
{
    int i = blockIdx.x * 256 + threadIdx.x;   // float4 group
    int base = i * 4;
    int row = base >> 11;          // n
    int col = base & 2047;         // k of first component
    int bn = row >> 7, bk = col >> 7;
    float w = (bk < bn) ? 16.0f : (bk == bn ? 8.0f : 0.0f);
    float4 v = ((const float4*)X)[i];
    float w0 = (col + 0 == row) ? 0.0f : w;
    float w1 = (col + 1 == row) ? 0.0f : w;
    float w2 = (col + 2 == row) ? 0.0f : w;
    float w3 = (col + 3 == row) ? 0.0f : w;
    uchar4 o;
    o.x = f32_to_fp8(v.x * w0); o.y = f32_to_fp8(v.y * w1);
    o.z = f32_to_fp8(v.z * w2); o.w = f32_to_fp8(v.w * w3);
    ((uchar4*)O)[i] = o;
}

// extract cov diagonal -> fp32 Cd[2048]
__global__ __launch_bounds__(256) void conv_covd_kernel(
    const float* __restrict__ X, float* __restrict__ Cd)
{
    int i = blockIdx.x * 256 + threadIdx.x;
    if (i < RFF) Cd[i] = X[(size_t)i * RFF + i];
}

// Phi16 (cos/32, bf16) -> Phi8 = e4m3(cos) (x32 prescale, exact exponent shift)
__global__ __launch_bounds__(256) void conv_phi8_kernel(
    const unsigned short* __restrict__ Phi16, unsigned char* __restrict__ Phi8)
{
    int i = blockIdx.x * 256 + threadIdx.x;
    ushort4 v = ((const ushort4*)Phi16)[i];
    uchar4 o;
    o.x = f32_to_fp8(bf16_to_f32(v.x) * 32.0f);
    o.y = f32_to_fp8(bf16_to_f32(v.y) * 32.0f);
    o.z = f32_to_fp8(bf16_to_f32(v.z) * 32.0f);
    o.w = f32_to_fp8(bf16_to_f32(v.w) * 32.0f);
    ((uchar4*)Phi8)[i] = o;
}

// Lw [1000,2048] fp32 -> [1024,2048] bf16, zero-padded rows
__global__ __launch_bounds__(256) void conv_lw_kernel(
    const float* __restrict__ Lw, unsigned short* __restrict__ O)
{
    int i = blockIdx.x * 256 + threadIdx.x;
    int base = i * 4;
    int row = base >> 11;
    ushort4 o;
    if (row < OUT_F) {
        float4 v = ((const float4*)Lw)[i];
        o.x = f32_to_bf16(v.x); o.y = f32_to_bf16(v.y);
        o.z = f32_to_bf16(v.z); o.w = f32_to_bf16(v.w);
    } else {
        o.x = o.y = o.z = o.w = 0;
    }
    ((ushort4*)O)[i] = o;
}

// W [512,2048] fp32 -> Wt hi/lo [2048,512] bf16 (transposed), 64x64 tiles
__global__ __launch_bounds__(256) void conv_wt_kernel(
    const float* __restrict__ W, unsigned short* __restrict__ TH,
    unsigned short* __restrict__ TL)
{
    __shared__ float tile[64][65];
    const int tid = threadIdx.x;
    const int n0 = blockIdx.x * 64;
    const int k0 = blockIdx.y * 64;
    #pragma unroll
    for (int i = 0; i < 16; ++i) {
        int e = i * 256 + tid;
        int r = e >> 6, c = e & 63;
        tile[r][c] = W[(size_t)(k0 + r) * RFF + n0 + c];
    }
    __syncthreads();
    #pragma unroll
    for (int i = 0; i < 16; ++i) {
        int e = i * 256 + tid;
        int r = e >> 6, c = e & 63;
        float v = tile[c][r];
        unsigned short h = f32_to_bf16(v);
        unsigned short l = f32_to_bf16(v - bf16_to_f32(h));
        TH[(size_t)(n0 + r) * IN_F + k0 + c] = h;
        TL[(size_t)(n0 + r) * IN_F + k0 + c] = l;
    }
}

// ---------------- Kernel 1: Phi = cos(D@W + b)/32 (split bf16 MFMA) ----------------
__global__ __launch_bounds__(256) void phi_mfma_kernel(
    const unsigned short* __restrict__ Dh, const unsigned short* __restrict__ Dl,
    const unsigned short* __restrict__ Wth, const unsigned short* __restrict__ Wtl,
    const float* __restrict__ bias, unsigned short* __restrict__ Phi)
{
    __shared__ unsigned short ldsAh[4096], ldsAl[4096], ldsBh[4096], ldsBl[4096];
    const int tid = threadIdx.x;
    const int w = tid >> 6, lane = tid & 63;
    const int wm = w >> 1, wn = w & 1;
    const int r0 = blockIdx.y * 128;
    const int c0 = blockIdx.x * 128;

    f32x4 acc[4][4];
    #pragma unroll
    for (int i = 0; i < 4; ++i)
        #pragma unroll
        for (int j = 0; j < 4; ++j)
            acc[i][j] = (f32x4)(0.0f);

    for (int k0 = 0; k0 < IN_F; k0 += 32) {
        __syncthreads();
        stage_tile(Dh,  IN_F, r0, k0, ldsAh, w, lane);
        stage_tile(Dl,  IN_F, r0, k0, ldsAl, w, lane);
        stage_tile(Wth, IN_F, c0, k0, ldsBh, w, lane);
        stage_tile(Wtl, IN_F, c0, k0, ldsBl, w, lane);
        __syncthreads();

        short8 fah[4], fal[4], fbh[4], fbl[4];
        #pragma unroll
        for (int t = 0; t < 4; ++t) {
            fah[t] = *(const short8*)(ldsAh + ((wm * 4 + t) * 64 + lane) * 8);
            fal[t] = *(const short8*)(ldsAl + ((wm * 4 + t) * 64 + lane) * 8);
            fbh[t] = *(const short8*)(ldsBh + ((wn * 4 + t) * 64 + lane) * 8);
            fbl[t] = *(const short8*)(ldsBl + ((wn * 4 + t) * 64 + lane) * 8);
        }
        #pragma unroll
        for (int mt = 0; mt < 4; ++mt)
            #pragma unroll
            for (int nt = 0; nt < 4; ++nt) {
                acc[mt][nt] = __builtin_amdgcn_mfma_f32_16x16x32_bf16(
                    fah[mt], fbh[nt], acc[mt][nt], 0, 0, 0);
                acc[mt][nt] = __builtin_amdgcn_mfma_f32_16x16x32_bf16(
                    fah[mt], fbl[nt], acc[mt][nt], 0, 0, 0);
                acc[mt][nt] = __builtin_amdgcn_mfma_f32_16x16x32_bf16(
                    fal[mt], fbh[nt], acc[mt][nt], 0, 0, 0);
            }
    }

    const int quad = lane >> 4, ln = lane & 15;
    #pragma unroll
    for (int mt = 0; mt < 4; ++mt)
        #pragma unroll
        for (int nt = 0; nt < 4; ++nt) {
            int col = c0 + wn * 64 + nt * 16 + ln;
            float bv = bias[col];
            #pragma unroll
            for (int reg = 0; reg < 4; ++reg) {
                int row = r0 + wm * 64 + mt * 16 + quad * 4 + reg;
                float z = acc[mt][nt][reg] + bv;
                float p = __cosf(z) * INV_RFF_SCALAR;
                Phi[(size_t)row * RFF + col] = f32_to_bf16(p);
            }
        }
}

// ------- Fused kernel: diag blocks (fp8 off-diag + exact diag) + pred blocks -------
// 1536 blocks: b%3==2 -> pred (512), else diag (1024). 6 blocks/CU.
__global__ __launch_bounds__(256) void fused_dp_kernel(
    const unsigned short* __restrict__ Phi16, const unsigned char* __restrict__ Phi8,
    const unsigned char* __restrict__ CovU8, const float* __restrict__ Cd,
    const unsigned short* __restrict__ Lw, const float* __restrict__ Lb,
    float* __restrict__ diag, float* __restrict__ out)
{
    __shared__ __align__(16) unsigned char smem[16384];
    const int tid = threadIdx.x;
    const int w = tid >> 6, lane = tid & 63;
    const int wm = w >> 1, wn = w & 1;
    const int quad = lane >> 4, ln = lane & 15;
    const int b = blockIdx.x;

    f32x4 acc[4][4];
    #pragma unroll
    for (int i = 0; i < 4; ++i)
        #pragma unroll
        for (int j = 0; j < 4; ++j)
            acc[i][j] = (f32x4)(0.0f);

    if (b % 3 != 2) {
        // ---------------- diag role (fp8 e4m3, K-step 64 bytes) ----------------
        const int d = (b / 3) * 2 + (b % 3);           // 0..1023
        const int J = 15 - (d >> 6);                   // longest K dispatched first
        const int r0 = (d & 63) * 128;
        const int c0 = J * 128;
        const int kmaxb = (J + 1) * 128;
        unsigned char* ldsA8 = smem;
        unsigned char* ldsB8 = smem + 8192;

        for (int k0b = 0; k0b < kmaxb; k0b += 64) {
            __syncthreads();
            stage_tile8(Phi8,  RFF, r0, k0b, ldsA8, w, lane);
            stage_tile8(CovU8, RFF, c0, k0b, ldsB8, w, lane);
            __syncthreads();

            #pragma unroll
            for (int s = 0; s < 2; ++s) {
                const int ccol = s * 2 + (quad >> 1);
                const int off8 = (quad & 1) << 3;
                long fa[4], fb[4];
                #pragma unroll
                for (int t = 0; t < 4; ++t) {
                    fa[t] = *(const long*)(ldsA8 + (((wm * 4 + t) * 64 + ccol * 16 + ln) << 4) + off8);
                    fb[t] = *(const long*)(ldsB8 + (((wn * 4 + t) * 64 + ccol * 16 + ln) << 4) + off8);
                }
                #pragma unroll
                for (int mt = 0; mt < 4; ++mt)
                    #pragma unroll
                    for (int nt = 0; nt < 4; ++nt)
                        acc[mt][nt] = __builtin_amdgcn_mfma_f32_16x16x32_fp8_fp8(
                            fa[mt], fb[nt], acc[mt][nt], 0, 0, 0);
            }
        }

        // epilogue: ((M_off .* Phi) + Cd.*Phi^2) row-reduce.
        // acc = 512*M_off (32x Phi8, 16x CovU8); final scale 1/256 = 2/512
        // (triangle fold x2). Exact-diagonal term injected as +256*Cd*pv.
        float cd[4];
        #pragma unroll
        for (int nt = 0; nt < 4; ++nt)
            cd[nt] = 256.0f * Cd[c0 + wn * 64 + nt * 16 + ln];
        #pragma unroll
        for (int mt = 0; mt < 4; ++mt) {
            float psum[4] = {0.f, 0.f, 0.f, 0.f};
            #pragma unroll
            for (int nt = 0; nt < 4; ++nt) {
                int col = c0 + wn * 64 + nt * 16 + ln;
                #pragma unroll
                for (int reg = 0; reg < 4; ++reg) {
                    int row = r0 + wm * 64 + mt * 16 + quad * 4 + reg;
                    float pv = bf16_to_f32(Phi16[(size_t)row * RFF + col]);
                    psum[reg] = fmaf(fmaf(cd[nt], pv, acc[mt][nt][reg]), pv, psum[reg]);
                }
            }
            #pragma unroll
            for (int off = 1; off < 16; off <<= 1)
                #pragma unroll
                for (int reg = 0; reg < 4; ++reg)
                    psum[reg] += __shfl_xor(psum[reg], off, 16);
            if (ln == 0) {
                #pragma unroll
                for (int reg = 0; reg < 4; ++reg) {
                    int row = r0 + wm * 64 + mt * 16 + quad * 4 + reg;
                    atomicAdd(&diag[row], psum[reg] * (1.0f / 256.0f));
                }
            }
        }
    } else {
        // ---------------- pred role (bf16): out = Phi@Lw^T + Lb (unscaled) ----------------
        const int p = b / 3;                           // 0..511
        const int r0 = (p >> 3) * 128;
        const int c0 = (p & 7) * 128;
        unsigned short* ldsA = (unsigned short*)smem;
        unsigned short* ldsB = (unsigned short*)(smem + 8192);

        for (int k0 = 0; k0 < RFF; k0 += 32) {
            __syncthreads();
            stage_tile(Phi16, RFF, r0, k0, ldsA, w, lane);
            stage_tile(Lw,    RFF, c0, k0, ldsB, w, lane);
            __syncthreads();

            short8 fa[4], fb[4];
            #pragma unroll
            for (int t = 0; t < 4; ++t) {
                fa[t] = *(const short8*)(ldsA + ((wm * 4 + t) * 64 + lane) * 8);
                fb[t] = *(const short8*)(ldsB + ((wn * 4 + t) * 64 + lane) * 8);
            }
            #pragma unroll
            for (int mt = 0; mt < 4; ++mt)
                #pragma unroll
                for (int nt = 0; nt < 4; ++nt)
                    acc[mt][nt] = __builtin_amdgcn_mfma_f32_16x16x32_bf16(
                        fa[mt], fb[nt], acc[mt][nt], 0, 0, 0);
        }

        #pragma unroll
        for (int mt = 0; mt < 4; ++mt)
            #pragma unroll
            for (int nt = 0; nt < 4; ++nt) {
                int col = c0 + wn * 64 + nt * 16 + ln;
                if (col < OUT_F) {
                    float bv = Lb[col];
                    #pragma unroll
                    for (int reg = 0; reg < 4; ++reg) {
                        int row = r0 + wm * 64 + mt * 16 + quad * 4 + reg;
                        out[(size_t)row * OUT_F + col] = acc[mt][nt][reg] + bv;
                    }
                }
            }
    }
}

// ---------------- final: out *= 1/sqrt(1+25*diag[row]), in place ----------------
__global__ __launch_bounds__(256) void scale_kernel(
    float* __restrict__ out, const float* __restrict__ diag)
{
    const int row = blockIdx.x;
    const int t = threadIdx.x;
    float s = 1.0f / sqrtf(1.0f + MEAN_FIELD * diag[row]);
    if (t < 250) {   // 1000 floats = 250 float4 per row
        float4* p = (float4*)(out + (size_t)row * OUT_F);
        float4 v = p[t];
        v.x *= s; v.y *= s; v.z *= s; v.w *= s;
        p[t] = v;
    }
}

extern "C" void kernel_launch(void* const* d_in, const int* in_sizes, int n_in,
                              void* d_out, int out_size, void* d_ws, size_t ws_size,
                              hipStream_t stream) {
    const float* D    = (const float*)d_in[0];
    const float* W    = (const float*)d_in[1];
    const float* bias = (const float*)d_in[2];
    const float* Lw   = (const float*)d_in[3];
    const float* Lb   = (const float*)d_in[4];
    const float* cov  = (const float*)d_in[5];
    float* out = (float*)d_out;

    // workspace layout — same footprint as round 5.
    // Phi8 (16 MiB) aliases Dh+Dl (dead after phi_mfma);
    // Cd (8 KiB) lives in the unused second half of the CovU8 region.
    char* p = (char*)d_ws;
    unsigned short* Phi16 = (unsigned short*)p;  p += (size_t)N_ROWS * RFF * 2;   // 32 MiB
    unsigned char*  Phi8  = (unsigned char*)p;   // alias of Dh+Dl region (16 MiB)
    unsigned short* Dh    = (unsigned short*)p;  p += (size_t)N_ROWS * IN_F * 2;  // 8 MiB
    unsigned short* Dl    = (unsigned short*)p;  p += (size_t)N_ROWS * IN_F * 2;  // 8 MiB
    unsigned short* Wth   = (unsigned short*)p;  p += (size_t)RFF * IN_F * 2;     // 2 MiB
    unsigned short* Wtl   = (unsigned short*)p;  p += (size_t)RFF * IN_F * 2;     // 2 MiB
    unsigned short* Lw16  = (unsigned short*)p;  p += (size_t)OUT_PAD * RFF * 2;  // 4 MiB
    unsigned char*  CovU8 = (unsigned char*)p;                                    // 4 MiB used
    float*          Cd    = (float*)(p + (size_t)RFF * RFF);                      // 8 KiB (in pad)
    p += (size_t)RFF * RFF * 2;                                                   // 8 MiB region
    float* diag           = (float*)p;                                            // 32 KiB

    hipMemsetAsync(diag, 0, N_ROWS * sizeof(float), stream);

    dim3 blk(256);
    conv_split_kernel<<<dim3((N_ROWS * IN_F / 4 + 255) / 256), blk, 0, stream>>>(D, Dh, Dl, N_ROWS * IN_F / 4);
    conv_wt_kernel<<<dim3(RFF / 64, IN_F / 64), blk, 0, stream>>>(W, Wth, Wtl);
    conv_lw_kernel<<<dim3(OUT_PAD * RFF / 4 / 256), blk, 0, stream>>>(Lw, Lw16);
    conv_covu8_kernel<<<dim3(RFF * RFF / 4 / 256), blk, 0, stream>>>(cov, CovU8);
    conv_covd_kernel<<<dim3(RFF / 256), blk, 0, stream>>>(cov, Cd);

    phi_mfma_kernel<<<dim3(RFF / 128, N_ROWS / 128), blk, 0, stream>>>(Dh, Dl, Wth, Wtl, bias, Phi16);
    conv_phi8_kernel<<<dim3(N_ROWS * RFF / 4 / 256), blk, 0, stream>>>(Phi16, Phi8);

    fused_dp_kernel<<<dim3(1536), blk, 0, stream>>>(Phi16, Phi8, CovU8, Cd, Lw16, Lb, diag, out);
    scale_kernel<<<dim3(N_ROWS), blk, 0, stream>>>(out, diag);
}

// Round 8
// 318.621 us; speedup vs baseline: 1.1464x; 1.1464x over previous
//
#include <hip/hip_runtime.h>
#include <hip/hip_fp8.h>
#include <math.h>

#define N_ROWS 8192
#define IN_F   512
#define RFF    2048
#define OUT_F  1000
#define OUT_PAD 1024
#define INV_RFF_SCALAR 0.03125f
#define MEAN_FIELD 25.0f

typedef __attribute__((ext_vector_type(8))) short short8;
typedef __attribute__((ext_vector_type(4))) float f32x4;
typedef __attribute__((ext_vector_type(2))) long long2v;

// ---------- bf16 helpers (RTN-even) ----------
__device__ __forceinline__ unsigned short f32_to_bf16(float f) {
    unsigned u = __float_as_uint(f);
    unsigned r = 0x7FFFu + ((u >> 16) & 1u);
    return (unsigned short)((u + r) >> 16);
}
__device__ __forceinline__ float bf16_to_f32(unsigned short h) {
    return __uint_as_float(((unsigned)h) << 16);
}
__device__ __forceinline__ unsigned char f32_to_fp8(float x) {
    __hip_fp8_e4m3 q(x);           // OCP e4m3fn, HW RNE convert
    return (unsigned char)q.__x;
}

// fp8 permuted packing within each 64-element k-block:
// pos(k) = (k & ~63) + quad*16 + s*8 + j   (quad=(k>>3)&3, s=(k>>5)&1, j=k&7)
// => lane (quad,ln)'s two 8B MFMA slices (s=0,1) are CONTIGUOUS 16B.
__device__ __forceinline__ int perm64(int k) {
    return (k & ~63) | (((k >> 3) & 3) << 4) | (((k >> 5) & 1) << 3) | (k & 7);
}

// ---- bf16 staging, K=32 tile (phi kernel; r5-validated) ----
__device__ __forceinline__ const uint4* gsrc(const unsigned short* X, int ldx,
                                             int r0, int k0, int q) {
    int rt = q >> 6, L = q & 63;
    int r = r0 + rt * 16 + (L & 15);
    int k = k0 + ((L >> 4) << 3);
    return (const uint4*)(X + (size_t)r * ldx + k);
}
__device__ __forceinline__ void stage_tile(const unsigned short* __restrict__ X, int ldx,
                                           int r0, int k0, unsigned short* lds,
                                           int w, int lane) {
    #pragma unroll
    for (int half = 0; half < 2; ++half) {
        int qb = half * 256 + w * 64;
        const uint4* g = gsrc(X, ldx, r0, k0, qb + lane);
        __builtin_amdgcn_global_load_lds(
            (const __attribute__((address_space(1))) void*)g,
            (__attribute__((address_space(3))) void*)(lds + qb * 8),
            16, 0, 0);
    }
}

// ---- bf16 staging, K=64 tile (pred): 1024 chunks, q = rt*128 + c*16 + r ----
// chunk carries row rt*16+r, elems k0 + c*8 .. +8
__device__ __forceinline__ void stage_tile64(const unsigned short* __restrict__ X,
                                             int r0, int k0, unsigned char* lds,
                                             int w, int lane) {
    #pragma unroll
    for (int h = 0; h < 4; ++h) {
        int qb = h * 256 + w * 64;
        int q = qb + lane;
        int rt = q >> 7, c = (q >> 4) & 7, r = q & 15;
        const void* g = X + (size_t)(r0 + rt * 16 + r) * RFF + k0 + c * 8;
        __builtin_amdgcn_global_load_lds(
            (const __attribute__((address_space(1))) void*)g,
            (__attribute__((address_space(3))) void*)(lds + qb * 16),
            16, 0, 0);
    }
}

// ---- fp8 staging, K=128-byte tile (diag): 1024 chunks, q = rt*128 + c*16 + r ----
// X is packed (perm64); chunk carries row rt*16+r, packed bytes k0b + c*16 .. +16
__device__ __forceinline__ void stage_tile8(const unsigned char* __restrict__ X,
                                            int r0, int k0b, unsigned char* lds,
                                            int w, int lane) {
    #pragma unroll
    for (int h = 0; h < 4; ++h) {
        int qb = h * 256 + w * 64;
        int q = qb + lane;
        int rt = q >> 7, c = (q >> 4) & 7, r = q & 15;
        const void* g = X + (size_t)(r0 + rt * 16 + r) * RFF + k0b + c * 16;
        __builtin_amdgcn_global_load_lds(
            (const __attribute__((address_space(1))) void*)g,
            (__attribute__((address_space(3))) void*)(lds + qb * 16),
            16, 0, 0);
    }
}

// ---------------- conversion kernels ----------------
__global__ __launch_bounds__(256) void conv_split_kernel(
    const float* __restrict__ X, unsigned short* __restrict__ H,
    unsigned short* __restrict__ L, int n4)
{
    int i = blockIdx.x * 256 + threadIdx.x;
    if (i >= n4) return;
    float4 v = ((const float4*)X)[i];
    ushort4 h, l;
    h.x = f32_to_bf16(v.x); l.x = f32_to_bf16(v.x - bf16_to_f32(h.x));
    h.y = f32_to_bf16(v.y); l.y = f32_to_bf16(v.y - bf16_to_f32(h.y));
    h.z = f32_to_bf16(v.z); l.z = f32_to_bf16(v.z - bf16_to_f32(h.z));
    h.w = f32_to_bf16(v.w); l.w = f32_to_bf16(v.w - bf16_to_f32(h.w));
    ((ushort4*)H)[i] = h;
    ((ushort4*)L)[i] = l;
}

// cov -> fp8 e4m3, B^T layout, PERMUTED k-packing, block-triangular weights
// {16,8,0} (blk=128), diagonal entries zeroed (added exactly via Cd).
__global__ __launch_bounds__(256) void conv_covu8_kernel(
    const float* __restrict__ X, unsigned char* __restrict__ O)
{
    int i = blockIdx.x * 256 + threadIdx.x;   // float4 group
    int base = i * 4;
    int row = base >> 11;          // n
    int col = base & 2047;         // k of first component
    int bn = row >> 7, bk = col >> 7;
    float w = (bk < bn) ? 16.0f : (bk == bn ? 8.0f : 0.0f);
    float4 v = ((const float4*)X)[i];
    float w0 = (col + 0 == row) ? 0.0f : w;
    float w1 = (col + 1 == row) ? 0.0f : w;
    float w2 = (col + 2 == row) ? 0.0f : w;
    float w3 = (col + 3 == row) ? 0.0f : w;
    uchar4 o;
    o.x = f32_to_fp8(v.x * w0); o.y = f32_to_fp8(v.y * w1);
    o.z = f32_to_fp8(v.z * w2); o.w = f32_to_fp8(v.w * w3);
    *(uchar4*)(O + (size_t)row * RFF + perm64(col)) = o;
}

// extract cov diagonal -> fp32 Cd[2048]
__global__ __launch_bounds__(256) void conv_covd_kernel(
    const float* __restrict__ X, float* __restrict__ Cd)
{
    int i = blockIdx.x * 256 + threadIdx.x;
    if (i < RFF) Cd[i] = X[(size_t)i * RFF + i];
}

// Phi16 (cos/32, bf16) -> Phi8 = e4m3(cos), permuted packing
__global__ __launch_bounds__(256) void conv_phi8_kernel(
    const unsigned short* __restrict__ Phi16, unsigned char* __restrict__ Phi8)
{
    int i = blockIdx.x * 256 + threadIdx.x;
    int base = i * 4;
    int row = base >> 11;
    int col = base & 2047;
    ushort4 v = ((const ushort4*)Phi16)[i];
    uchar4 o;
    o.x = f32_to_fp8(bf16_to_f32(v.x) * 32.0f);
    o.y = f32_to_fp8(bf16_to_f32(v.y) * 32.0f);
    o.z = f32_to_fp8(bf16_to_f32(v.z) * 32.0f);
    o.w = f32_to_fp8(bf16_to_f32(v.w) * 32.0f);
    *(uchar4*)(Phi8 + (size_t)row * RFF + perm64(col)) = o;
}

// Lw [1000,2048] fp32 -> [1024,2048] bf16, zero-padded rows
__global__ __launch_bounds__(256) void conv_lw_kernel(
    const float* __restrict__ Lw, unsigned short* __restrict__ O)
{
    int i = blockIdx.x * 256 + threadIdx.x;
    int base = i * 4;
    int row = base >> 11;
    ushort4 o;
    if (row < OUT_F) {
        float4 v = ((const float4*)Lw)[i];
        o.x = f32_to_bf16(v.x); o.y = f32_to_bf16(v.y);
        o.z = f32_to_bf16(v.z); o.w = f32_to_bf16(v.w);
    } else {
        o.x = o.y = o.z = o.w = 0;
    }
    ((ushort4*)O)[i] = o;
}

// W [512,2048] fp32 -> Wt hi/lo [2048,512] bf16 (transposed), 64x64 tiles
__global__ __launch_bounds__(256) void conv_wt_kernel(
    const float* __restrict__ W, unsigned short* __restrict__ TH,
    unsigned short* __restrict__ TL)
{
    __shared__ float tile[64][65];
    const int tid = threadIdx.x;
    const int n0 = blockIdx.x * 64;
    const int k0 = blockIdx.y * 64;
    #pragma unroll
    for (int i = 0; i < 16; ++i) {
        int e = i * 256 + tid;
        int r = e >> 6, c = e & 63;
        tile[r][c] = W[(size_t)(k0 + r) * RFF + n0 + c];
    }
    __syncthreads();
    #pragma unroll
    for (int i = 0; i < 16; ++i) {
        int e = i * 256 + tid;
        int r = e >> 6, c = e & 63;
        float v = tile[c][r];
        unsigned short h = f32_to_bf16(v);
        unsigned short l = f32_to_bf16(v - bf16_to_f32(h));
        TH[(size_t)(n0 + r) * IN_F + k0 + c] = h;
        TL[(size_t)(n0 + r) * IN_F + k0 + c] = l;
    }
}

// ---------------- Kernel 1: Phi = cos(D@W + b)/32 (split bf16 MFMA) ----------------
__global__ __launch_bounds__(256) void phi_mfma_kernel(
    const unsigned short* __restrict__ Dh, const unsigned short* __restrict__ Dl,
    const unsigned short* __restrict__ Wth, const unsigned short* __restrict__ Wtl,
    const float* __restrict__ bias, unsigned short* __restrict__ Phi)
{
    __shared__ unsigned short ldsAh[4096], ldsAl[4096], ldsBh[4096], ldsBl[4096];
    const int tid = threadIdx.x;
    const int w = tid >> 6, lane = tid & 63;
    const int wm = w >> 1, wn = w & 1;
    const int r0 = blockIdx.y * 128;
    const int c0 = blockIdx.x * 128;

    f32x4 acc[4][4];
    #pragma unroll
    for (int i = 0; i < 4; ++i)
        #pragma unroll
        for (int j = 0; j < 4; ++j)
            acc[i][j] = (f32x4)(0.0f);

    for (int k0 = 0; k0 < IN_F; k0 += 32) {
        __syncthreads();
        stage_tile(Dh,  IN_F, r0, k0, ldsAh, w, lane);
        stage_tile(Dl,  IN_F, r0, k0, ldsAl, w, lane);
        stage_tile(Wth, IN_F, c0, k0, ldsBh, w, lane);
        stage_tile(Wtl, IN_F, c0, k0, ldsBl, w, lane);
        __syncthreads();

        short8 fah[4], fal[4], fbh[4], fbl[4];
        #pragma unroll
        for (int t = 0; t < 4; ++t) {
            fah[t] = *(const short8*)(ldsAh + ((wm * 4 + t) * 64 + lane) * 8);
            fal[t] = *(const short8*)(ldsAl + ((wm * 4 + t) * 64 + lane) * 8);
            fbh[t] = *(const short8*)(ldsBh + ((wn * 4 + t) * 64 + lane) * 8);
            fbl[t] = *(const short8*)(ldsBl + ((wn * 4 + t) * 64 + lane) * 8);
        }
        #pragma unroll
        for (int mt = 0; mt < 4; ++mt)
            #pragma unroll
            for (int nt = 0; nt < 4; ++nt) {
                acc[mt][nt] = __builtin_amdgcn_mfma_f32_16x16x32_bf16(
                    fah[mt], fbh[nt], acc[mt][nt], 0, 0, 0);
                acc[mt][nt] = __builtin_amdgcn_mfma_f32_16x16x32_bf16(
                    fah[mt], fbl[nt], acc[mt][nt], 0, 0, 0);
                acc[mt][nt] = __builtin_amdgcn_mfma_f32_16x16x32_bf16(
                    fal[mt], fbh[nt], acc[mt][nt], 0, 0, 0);
            }
    }

    const int quad = lane >> 4, ln = lane & 15;
    #pragma unroll
    for (int mt = 0; mt < 4; ++mt)
        #pragma unroll
        for (int nt = 0; nt < 4; ++nt) {
            int col = c0 + wn * 64 + nt * 16 + ln;
            float bv = bias[col];
            #pragma unroll
            for (int reg = 0; reg < 4; ++reg) {
                int row = r0 + wm * 64 + mt * 16 + quad * 4 + reg;
                float z = acc[mt][nt][reg] + bv;
                float p = __cosf(z) * INV_RFF_SCALAR;
                Phi[(size_t)row * RFF + col] = f32_to_bf16(p);
            }
        }
}

// ------- Kernel 2: diag via fp8 (off-diag) + exact diagonal; triangular K -------
// K-step 128 bytes; fragment reads are single ds_read_b128 (conflict-free pattern).
__global__ __launch_bounds__(256) void diag8_kernel(
    const unsigned char* __restrict__ Phi8, const unsigned char* __restrict__ CovU8,
    const unsigned short* __restrict__ Phi16, const float* __restrict__ Cd,
    float* __restrict__ diag)
{
    __shared__ __align__(16) unsigned char ldsA[16384];
    __shared__ __align__(16) unsigned char ldsB[16384];
    const int tid = threadIdx.x;
    const int w = tid >> 6, lane = tid & 63;
    const int wm = w >> 1, wn = w & 1;
    const int quad = lane >> 4, ln = lane & 15;
    const int J = 15 - blockIdx.x;          // longest K first in dispatch order mix
    const int r0 = blockIdx.y * 128;
    const int c0 = J * 128;
    const int kmax = (J + 1) * 128;

    f32x4 acc[4][4];
    #pragma unroll
    for (int i = 0; i < 4; ++i)
        #pragma unroll
        for (int j = 0; j < 4; ++j)
            acc[i][j] = (f32x4)(0.0f);

    for (int k0 = 0; k0 < kmax; k0 += 128) {
        __syncthreads();
        stage_tile8(Phi8,  r0, k0, ldsA, w, lane);
        stage_tile8(CovU8, c0, k0, ldsB, w, lane);
        __syncthreads();

        #pragma unroll
        for (int kb = 0; kb < 2; ++kb) {
            long2v fa[4], fb[4];
            #pragma unroll
            for (int t = 0; t < 4; ++t) {
                fa[t] = *(const long2v*)(ldsA + (((wm * 4 + t) * 128 + (kb * 4 + quad) * 16 + ln) << 4));
                fb[t] = *(const long2v*)(ldsB + (((wn * 4 + t) * 128 + (kb * 4 + quad) * 16 + ln) << 4));
            }
            #pragma unroll
            for (int mt = 0; mt < 4; ++mt)
                #pragma unroll
                for (int nt = 0; nt < 4; ++nt)
                    acc[mt][nt] = __builtin_amdgcn_mfma_f32_16x16x32_fp8_fp8(
                        fa[mt].x, fb[nt].x, acc[mt][nt], 0, 0, 0);
            #pragma unroll
            for (int mt = 0; mt < 4; ++mt)
                #pragma unroll
                for (int nt = 0; nt < 4; ++nt)
                    acc[mt][nt] = __builtin_amdgcn_mfma_f32_16x16x32_fp8_fp8(
                        fa[mt].y, fb[nt].y, acc[mt][nt], 0, 0, 0);
        }
    }

    // epilogue: ((M_off .* Phi) + Cd.*Phi^2) row-reduce; acc = 512*M_off;
    // scale 1/256 = 2/512 (triangle fold). Exact diagonal as +256*Cd*pv.
    float cd[4];
    #pragma unroll
    for (int nt = 0; nt < 4; ++nt)
        cd[nt] = 256.0f * Cd[c0 + wn * 64 + nt * 16 + ln];
    #pragma unroll
    for (int mt = 0; mt < 4; ++mt) {
        float psum[4] = {0.f, 0.f, 0.f, 0.f};
        #pragma unroll
        for (int nt = 0; nt < 4; ++nt) {
            int col = c0 + wn * 64 + nt * 16 + ln;
            #pragma unroll
            for (int reg = 0; reg < 4; ++reg) {
                int row = r0 + wm * 64 + mt * 16 + quad * 4 + reg;
                float pv = bf16_to_f32(Phi16[(size_t)row * RFF + col]);
                psum[reg] = fmaf(fmaf(cd[nt], pv, acc[mt][nt][reg]), pv, psum[reg]);
            }
        }
        #pragma unroll
        for (int off = 1; off < 16; off <<= 1)
            #pragma unroll
            for (int reg = 0; reg < 4; ++reg)
                psum[reg] += __shfl_xor(psum[reg], off, 16);
        if (ln == 0) {
            #pragma unroll
            for (int reg = 0; reg < 4; ++reg) {
                int row = r0 + wm * 64 + mt * 16 + quad * 4 + reg;
                atomicAdd(&diag[row], psum[reg] * (1.0f / 256.0f));
            }
        }
    }
}

// ---- Kernel 3: out = (Phi@LwT + Lb) / sqrt(1+25*diag), bf16, K-step 64 ----
__global__ __launch_bounds__(256) void pred_mfma_kernel(
    const unsigned short* __restrict__ Phi, const unsigned short* __restrict__ Lw,
    const float* __restrict__ Lb, const float* __restrict__ diag,
    float* __restrict__ out)
{
    __shared__ __align__(16) unsigned char ldsA[16384];
    __shared__ __align__(16) unsigned char ldsB[16384];
    const int tid = threadIdx.x;
    const int w = tid >> 6, lane = tid & 63;
    const int wm = w >> 1, wn = w & 1;
    const int quad = lane >> 4, ln = lane & 15;
    const int r0 = blockIdx.y * 128;
    const int c0 = blockIdx.x * 128;

    f32x4 acc[4][4];
    #pragma unroll
    for (int i = 0; i < 4; ++i)
        #pragma unroll
        for (int j = 0; j < 4; ++j)
            acc[i][j] = (f32x4)(0.0f);

    for (int k0 = 0; k0 < RFF; k0 += 64) {
        __syncthreads();
        stage_tile64(Phi, r0, k0, ldsA, w, lane);
        stage_tile64(Lw,  c0, k0, ldsB, w, lane);   // Lw is [out,rff] = B^T layout
        __syncthreads();

        #pragma unroll
        for (int s = 0; s < 2; ++s) {
            short8 fa[4], fb[4];
            #pragma unroll
            for (int t = 0; t < 4; ++t) {
                fa[t] = *(const short8*)(ldsA + (((wm * 4 + t) * 128 + (s * 4 + quad) * 16 + ln) << 4));
                fb[t] = *(const short8*)(ldsB + (((wn * 4 + t) * 128 + (s * 4 + quad) * 16 + ln) << 4));
            }
            #pragma unroll
            for (int mt = 0; mt < 4; ++mt)
                #pragma unroll
                for (int nt = 0; nt < 4; ++nt)
                    acc[mt][nt] = __builtin_amdgcn_mfma_f32_16x16x32_bf16(
                        fa[mt], fb[nt], acc[mt][nt], 0, 0, 0);
        }
    }

    #pragma unroll
    for (int mt = 0; mt < 4; ++mt) {
        float s[4];
        #pragma unroll
        for (int reg = 0; reg < 4; ++reg) {
            int row = r0 + wm * 64 + mt * 16 + quad * 4 + reg;
            s[reg] = 1.0f / sqrtf(1.0f + MEAN_FIELD * diag[row]);
        }
        #pragma unroll
        for (int nt = 0; nt < 4; ++nt) {
            int col = c0 + wn * 64 + nt * 16 + ln;
            if (col < OUT_F) {
                float bv = Lb[col];
                #pragma unroll
                for (int reg = 0; reg < 4; ++reg) {
                    int row = r0 + wm * 64 + mt * 16 + quad * 4 + reg;
                    out[(size_t)row * OUT_F + col] = (acc[mt][nt][reg] + bv) * s[reg];
                }
            }
        }
    }
}

extern "C" void kernel_launch(void* const* d_in, const int* in_sizes, int n_in,
                              void* d_out, int out_size, void* d_ws, size_t ws_size,
                              hipStream_t stream) {
    const float* D    = (const float*)d_in[0];
    const float* W    = (const float*)d_in[1];
    const float* bias = (const float*)d_in[2];
    const float* Lw   = (const float*)d_in[3];
    const float* Lb   = (const float*)d_in[4];
    const float* cov  = (const float*)d_in[5];
    float* out = (float*)d_out;

    // workspace — Phi8 (16 MiB) aliases Dh+Dl (dead after phi_mfma);
    // Cd (8 KiB) in the unused half of the CovU8 region.
    char* p = (char*)d_ws;
    unsigned short* Phi16 = (unsigned short*)p;  p += (size_t)N_ROWS * RFF * 2;   // 32 MiB
    unsigned char*  Phi8  = (unsigned char*)p;   // alias of Dh+Dl region (16 MiB)
    unsigned short* Dh    = (unsigned short*)p;  p += (size_t)N_ROWS * IN_F * 2;  // 8 MiB
    unsigned short* Dl    = (unsigned short*)p;  p += (size_t)N_ROWS * IN_F * 2;  // 8 MiB
    unsigned short* Wth   = (unsigned short*)p;  p += (size_t)RFF * IN_F * 2;     // 2 MiB
    unsigned short* Wtl   = (unsigned short*)p;  p += (size_t)RFF * IN_F * 2;     // 2 MiB
    unsigned short* Lw16  = (unsigned short*)p;  p += (size_t)OUT_PAD * RFF * 2;  // 4 MiB
    unsigned char*  CovU8 = (unsigned char*)p;                                    // 4 MiB used
    float*          Cd    = (float*)(p + (size_t)RFF * RFF);                      // 8 KiB (in pad)
    p += (size_t)RFF * RFF * 2;                                                   // 8 MiB region
    float* diag           = (float*)p;                                            // 32 KiB

    hipMemsetAsync(diag, 0, N_ROWS * sizeof(float), stream);

    dim3 blk(256);
    conv_split_kernel<<<dim3((N_ROWS * IN_F / 4 + 255) / 256), blk, 0, stream>>>(D, Dh, Dl, N_ROWS * IN_F / 4);
    conv_wt_kernel<<<dim3(RFF / 64, IN_F / 64), blk, 0, stream>>>(W, Wth, Wtl);
    conv_lw_kernel<<<dim3(OUT_PAD * RFF / 4 / 256), blk, 0, stream>>>(Lw, Lw16);
    conv_covu8_kernel<<<dim3(RFF * RFF / 4 / 256), blk, 0, stream>>>(cov, CovU8);
    conv_covd_kernel<<<dim3(RFF / 256), blk, 0, stream>>>(cov, Cd);

    phi_mfma_kernel<<<dim3(RFF / 128, N_ROWS / 128), blk, 0, stream>>>(Dh, Dl, Wth, Wtl, bias, Phi16);
    conv_phi8_kernel<<<dim3(N_ROWS * RFF / 4 / 256), blk, 0, stream>>>(Phi16, Phi8);

    diag8_kernel<<<dim3(16, N_ROWS / 128), blk, 0, stream>>>(Phi8, CovU8, Phi16, Cd, diag);
    pred_mfma_kernel<<<dim3(OUT_PAD / 128, N_ROWS / 128), blk, 0, stream>>>(Phi16, Lw16, Lb, diag, out);
}